// Round 16
// baseline (176.104 us; speedup 1.0000x reference)
//
#include <hip/hip_runtime.h>
#include <hip/hip_bf16.h>

// GCNConv: out = segment_sum(edge_vals * (x@W)[edge_col], edge_row)
// Phase 1: Wt = bf16(W^T); h = x@W via bf16 MFMA. x staged COALESCED into a
//          bf16 LDS tile (64 rows x 528B, reg-converted f2bf during staging;
//          one wave reads one full 1KB row per load instruction). K-loop is
//          pure ds_read_b128(A) + global wt(B) + MFMA -- no f2bf, no strided
//          16-line gathers.
// Phase 2: ATOMIC-FREE bucket counting sort (bucket = 64 rows):
//   hist -> colscan -> basescan -> scatter (LDS atomics only) ->
//   bucket_rowsum (gather unrolled x8).

#define IN_F  256
#define OUT_F 128
#define BSH   6        // 64 rows per bucket
#define CH    4096     // edges per chunk block
#define CAP   1536     // LDS sorted-bucket capacity (avg 1024, +16 sigma)
#define XLS   264      // x LDS row stride in ushorts (528B: bank-uniform)

typedef __attribute__((ext_vector_type(8))) short sh8;
typedef __attribute__((ext_vector_type(4))) float f32x4;

__device__ __forceinline__ unsigned short f2bf(float f) {
    unsigned u = __float_as_uint(f);
    unsigned r = u + 0x7fff + ((u >> 16) & 1);   // round-to-nearest-even
    return (unsigned short)(r >> 16);
}
__device__ __forceinline__ float bf2f(unsigned short s) {
    return __uint_as_float(((unsigned)s) << 16);
}

// ---------------- Wt[n][k] = bf16(W[k][n]) ----------------
__global__ __launch_bounds__(256) void wt_prep_kernel(
    const float* __restrict__ w, unsigned short* __restrict__ wt) {
    int i = blockIdx.x * 256 + threadIdx.x;     // 32768 elements
    int k = i >> 7, n = i & 127;
    wt[n * IN_F + k] = f2bf(w[i]);
}

// ---------------- h = x@W via MFMA, bf16 LDS x-tile ----------------
// Block: 256 thr = 4 waves, 64 rows. Stage: iter i, wave w loads row i*4+w
// fully coalesced (lane -> 16B granule), converts to bf16, ds_write_b64.
// Wave w computes rows w*16..w*16+15 x all 128 cols (acc[8]).
__global__ __launch_bounds__(256) void gemm_mfma_kernel(
    const float* __restrict__ x, const unsigned short* __restrict__ wt,
    unsigned short* __restrict__ h, int n_nodes) {
    __shared__ unsigned short xs[64 * XLS];      // 33 KB
    int tid = threadIdx.x;
    int w = tid >> 6, lane = tid & 63;
    long blk0 = (long)blockIdx.x * 64;
    long rmax = n_nodes - 1;

    // ---- coalesced stage + in-register bf16 convert ----
    #pragma unroll
    for (int it = 0; it < 16; it++) {
        int row = it * 4 + w;
        long grow = blk0 + row; if (grow > rmax) grow = rmax;
        float4 t = *(const float4*)(x + grow * IN_F + lane * 4);
        ushort4 o;
        o.x = f2bf(t.x); o.y = f2bf(t.y); o.z = f2bf(t.z); o.w = f2bf(t.w);
        *(ushort4*)(xs + row * XLS + lane * 4) = o;
    }
    __syncthreads();

    int l16 = lane & 15, hi = lane >> 4, lk = hi * 8;
    const unsigned short* xrow = xs + (w * 16 + l16) * XLS;
    const unsigned short* wp = wt + l16 * IN_F + lk;

    f32x4 acc[8];
    #pragma unroll
    for (int nt = 0; nt < 8; nt++)
        acc[nt] = (f32x4){0.f, 0.f, 0.f, 0.f};

    #pragma unroll
    for (int ks = 0; ks < 8; ks++) {
        int k0 = ks * 32;
        sh8 a = *(const sh8*)(xrow + k0 + lk);   // 16B, bank-uniform
        #pragma unroll
        for (int nt = 0; nt < 8; nt++) {
            sh8 b = *(const sh8*)(wp + nt * 16 * IN_F + k0);
            acc[nt] = __builtin_amdgcn_mfma_f32_16x16x32_bf16(
                a, b, acc[nt], 0, 0, 0);
        }
    }

    int rbase = hi * 4;
    #pragma unroll
    for (int j = 0; j < 4; j++) {
        long r = blk0 + w * 16 + rbase + j;
        if (r < n_nodes) {
            unsigned short* hp = h + r * OUT_F + l16;
            #pragma unroll
            for (int nt = 0; nt < 8; nt++)
                hp[nt * 16] = f2bf(acc[nt][j]);
        }
    }
}

// ---------------- hist: T[b][k] = #edges of block b in bucket k -----------
__global__ __launch_bounds__(256) void hist_kernel(
    const int* __restrict__ erow, int* __restrict__ T,
    int n_edges, int nbuck) {
    __shared__ int lh[2048];
    int tid = threadIdx.x, b = blockIdx.x;
    for (int k = tid; k < nbuck; k += 256) lh[k] = 0;
    __syncthreads();
    int s = b * CH, e = min(s + CH, n_edges);
    for (int i = s + tid; i < e; i += 256)
        atomicAdd(&lh[erow[i] >> BSH], 1);
    __syncthreads();
    int* Tr = T + (long)b * nbuck;
    for (int k = tid; k < nbuck; k += 256) Tr[k] = lh[k];
}

// ---------------- colscan: T[b][k] -> prefix over b; colTotal[k] ----------
__global__ __launch_bounds__(256) void colscan_kernel(
    int* __restrict__ T, int* __restrict__ colTotal, int nblk, int nbuck) {
    int k = blockIdx.x * 4 + (threadIdx.x >> 6);
    int lane = threadIdx.x & 63;
    if (k >= nbuck) return;
    int carry = 0;
    for (int c = 0; c < nblk; c += 64) {
        int b = c + lane;
        int v = (b < nblk) ? T[(long)b * nbuck + k] : 0;
        int incl = v;
        #pragma unroll
        for (int off = 1; off < 64; off <<= 1) {
            int t = __shfl_up(incl, off);
            if (lane >= off) incl += t;
        }
        if (b < nblk) T[(long)b * nbuck + k] = carry + incl - v;
        carry += __shfl(incl, 63);
    }
    if (lane == 0) colTotal[k] = carry;
}

// ---------------- basescan: bucketBase = exclusive scan(colTotal) ---------
__global__ __launch_bounds__(256) void basescan_kernel(
    const int* __restrict__ colTotal, int* __restrict__ base, int nbuck) {
    __shared__ int s[256];
    int tid = threadIdx.x;
    int loc[8];
    int sum = 0;
    #pragma unroll
    for (int j = 0; j < 8; j++) {
        int i = tid * 8 + j;
        loc[j] = (i < nbuck) ? colTotal[i] : 0;
        sum += loc[j];
    }
    s[tid] = sum;
    __syncthreads();
    for (int off = 1; off < 256; off <<= 1) {
        int t = (tid >= off) ? s[tid - off] : 0;
        __syncthreads();
        s[tid] += t;
        __syncthreads();
    }
    int pre = s[tid] - sum;
    #pragma unroll
    for (int j = 0; j < 8; j++) {
        int i = tid * 8 + j;
        if (i < nbuck) base[i] = pre;
        pre += loc[j];
    }
    if (tid == 255) base[nbuck] = pre;    // == n_edges
}

// ---------------- scatter: exact positions via LDS atomics ----------------
__global__ __launch_bounds__(256) void scatter_kernel(
    const int* __restrict__ erow, const int* __restrict__ ecol,
    const float* __restrict__ eval, const int* __restrict__ T,
    const int* __restrict__ base, unsigned long long* __restrict__ epack,
    int n_edges, int nbuck) {
    __shared__ int lpos[2048];
    int tid = threadIdx.x, b = blockIdx.x;
    const int* Tr = T + (long)b * nbuck;
    for (int k = tid; k < nbuck; k += 256) lpos[k] = base[k] + Tr[k];
    __syncthreads();
    int s = b * CH, e = min(s + CH, n_edges);
    for (int i = s + tid; i < e; i += 256) {
        int r = erow[i];
        int c = ecol[i];
        float v = eval[i];
        int p = atomicAdd(&lpos[r >> BSH], 1);
        epack[p] = ((unsigned long long)__float_as_uint(v) << 32)
                 | ((unsigned)(r & 63) << 17) | (unsigned)c;
    }
}

// ---------------- bucket_rowsum: block/bucket, LDS sort, gather x8 --------
__global__ __launch_bounds__(256) void bucket_rowsum_kernel(
    const unsigned short* __restrict__ h, const int* __restrict__ base,
    const unsigned long long* __restrict__ epack,
    float* __restrict__ out, int n_nodes, int nbuck) {
    __shared__ unsigned long long sorted[CAP];
    __shared__ int lh[64], lo[64], lc[64];
    int tid = threadIdx.x, k = blockIdx.x;
    int s = base[k], e = base[k + 1];
    int size = e - s;
    int wv = tid >> 6, lane = tid & 63;

    if (tid < 64) { lh[tid] = 0; lc[tid] = 0; }
    __syncthreads();
    for (int i = tid; i < size; i += 256) {
        unsigned lo32 = (unsigned)(epack[s + i] & 0xffffffffu);
        atomicAdd(&lh[(lo32 >> 17) & 63], 1);
    }
    __syncthreads();
    if (tid < 64) {
        int v = lh[tid];
        int incl = v;
        #pragma unroll
        for (int off = 1; off < 64; off <<= 1) {
            int t = __shfl_up(incl, off);
            if (lane >= off) incl += t;
        }
        lo[tid] = incl - v;
    }
    __syncthreads();
    bool fits = (size <= CAP);
    if (fits) {
        for (int i = tid; i < size; i += 256) {
            unsigned long long ed = epack[s + i];
            int r = (int)((ed >> 17) & 63);
            int p = atomicAdd(&lc[r], 1) + lo[r];
            sorted[p] = ed;
        }
    }
    __syncthreads();

#define GSTEP(EV)                                                            \
    {                                                                        \
        unsigned hv = *((const unsigned*)(h + (long)((EV) & 0x1ffffu) * OUT_F) + lane); \
        float vv = __uint_as_float((unsigned)((EV) >> 32));                  \
        a0 += vv * bf2f((unsigned short)(hv & 0xffff));                      \
        a1 += vv * bf2f((unsigned short)(hv >> 16));                         \
    }

    for (int rr = 0; rr < 16; rr++) {
        int r = wv * 16 + rr;
        long row = (long)k * 64 + r;
        if (row >= n_nodes) break;
        int rs = lo[r], cnt = lh[r];
        float a0 = 0.f, a1 = 0.f;
        if (fits) {
            int j = 0;
            for (; j + 8 <= cnt; j += 8) {
                unsigned long long e0 = sorted[rs + j];
                unsigned long long e1 = sorted[rs + j + 1];
                unsigned long long e2 = sorted[rs + j + 2];
                unsigned long long e3 = sorted[rs + j + 3];
                unsigned long long e4 = sorted[rs + j + 4];
                unsigned long long e5 = sorted[rs + j + 5];
                unsigned long long e6 = sorted[rs + j + 6];
                unsigned long long e7 = sorted[rs + j + 7];
                GSTEP(e0) GSTEP(e1) GSTEP(e2) GSTEP(e3)
                GSTEP(e4) GSTEP(e5) GSTEP(e6) GSTEP(e7)
            }
            for (; j + 4 <= cnt; j += 4) {
                unsigned long long e0 = sorted[rs + j];
                unsigned long long e1 = sorted[rs + j + 1];
                unsigned long long e2 = sorted[rs + j + 2];
                unsigned long long e3 = sorted[rs + j + 3];
                GSTEP(e0) GSTEP(e1) GSTEP(e2) GSTEP(e3)
            }
            for (; j < cnt; j++) {
                unsigned long long e0 = sorted[rs + j];
                GSTEP(e0)
            }
        } else {
            for (int i = 0; i < size; i++) {
                unsigned long long ed = epack[s + i];
                if ((int)((ed >> 17) & 63) == r) GSTEP(ed)
            }
        }
        float2 o; o.x = a0; o.y = a1;
        *(float2*)(out + row * OUT_F + lane * 2) = o;
    }
#undef GSTEP
}

extern "C" void kernel_launch(void* const* d_in, const int* in_sizes, int n_in,
                              void* d_out, int out_size, void* d_ws, size_t ws_size,
                              hipStream_t stream) {
    const float* x    = (const float*)d_in[0];
    const float* w    = (const float*)d_in[1];
    const int*   erow = (const int*)d_in[2];
    const int*   ecol = (const int*)d_in[3];
    const float* eval = (const float*)d_in[4];
    float* out = (float*)d_out;

    int n_nodes = in_sizes[0] / IN_F;
    int n_edges = in_sizes[2];
    int nbuck = (n_nodes + 63) >> BSH;            // 1563
    int nblk  = (n_edges + CH - 1) / CH;          // 391

    // workspace layout (256B aligned)
    char* p = (char*)d_ws;
    auto alloc = [&](size_t bytes) {
        char* q = p;
        p += (bytes + 255) & ~(size_t)255;
        return q;
    };
    unsigned short* h  = (unsigned short*)alloc((size_t)n_nodes * OUT_F * 2);
    int* T        = (int*)alloc((size_t)nblk * nbuck * 4);
    int* colTotal = (int*)alloc((size_t)nbuck * 4);
    int* base     = (int*)alloc((size_t)(nbuck + 1) * 4);
    unsigned long long* epack = (unsigned long long*)alloc((size_t)n_edges * 8);
    unsigned short* wt = (unsigned short*)alloc((size_t)IN_F * OUT_F * 2);

    wt_prep_kernel<<<dim3((IN_F * OUT_F) / 256), 256, 0, stream>>>(w, wt);
    gemm_mfma_kernel<<<dim3((n_nodes + 63) / 64), 256, 0, stream>>>(
        x, wt, h, n_nodes);

    hist_kernel<<<dim3(nblk), 256, 0, stream>>>(erow, T, n_edges, nbuck);
    colscan_kernel<<<dim3((nbuck + 3) / 4), 256, 0, stream>>>(
        T, colTotal, nblk, nbuck);
    basescan_kernel<<<dim3(1), 256, 0, stream>>>(colTotal, base, nbuck);
    scatter_kernel<<<dim3(nblk), 256, 0, stream>>>(
        erow, ecol, eval, T, base, epack, n_edges, nbuck);

    bucket_rowsum_kernel<<<dim3(nbuck), 256, 0, stream>>>(
        h, base, epack, out, n_nodes, nbuck);
}

// Round 18
// 167.831 us; speedup vs baseline: 1.0493x; 1.0493x over previous
//
#include <hip/hip_runtime.h>
#include <hip/hip_bf16.h>

// GCNConv: out = segment_sum(edge_vals * (x@W)[edge_col], edge_row)
// Phase 1: Wt = bf16(W^T); h = x@W via bf16 MFMA with SWAPPED operands
//          (A=wt, B=x): D rows = features -> each thread stores 4 adjacent
//          features as one ushort4 (16x 8B stores vs 64x 2B scalar stores).
//          Loads are identical to the R9 baseline.
// Phase 2: ATOMIC-FREE bucket counting sort (bucket = 64 rows):
//   hist -> colscan -> basescan -> scatter (LDS atomics only) ->
//   bucket_rowsum (gather unrolled x8).

#define IN_F  256
#define OUT_F 128
#define BSH   6        // 64 rows per bucket
#define CH    4096     // edges per chunk block
#define CAP   1536     // LDS sorted-bucket capacity (avg 1024, +16 sigma)

typedef __attribute__((ext_vector_type(8))) short sh8;
typedef __attribute__((ext_vector_type(4))) float f32x4;

__device__ __forceinline__ unsigned short f2bf(float f) {
    unsigned u = __float_as_uint(f);
    unsigned r = u + 0x7fff + ((u >> 16) & 1);   // round-to-nearest-even
    return (unsigned short)(r >> 16);
}
__device__ __forceinline__ float bf2f(unsigned short s) {
    return __uint_as_float(((unsigned)s) << 16);
}

// ---------------- Wt[n][k] = bf16(W[k][n]) ----------------
__global__ __launch_bounds__(256) void wt_prep_kernel(
    const float* __restrict__ w, unsigned short* __restrict__ wt) {
    int i = blockIdx.x * 256 + threadIdx.x;     // 32768 elements
    int k = i >> 7, n = i & 127;
    wt[n * IN_F + k] = f2bf(w[i]);
}

// ---------------- h = x@W via MFMA, swapped operands ----------------
// Block 256 = 4 waves; 128 rows (wave: 32 rows). A-frag = wt (M=features),
// B-frag = x (N=x-rows). D: col(l&15)=x-row, row((l>>4)*4+j)=feature.
// Store: thread writes 4 adjacent features per (rt,nt) as one ushort4.
__global__ __launch_bounds__(256) void gemm_mfma_kernel(
    const float* __restrict__ x, const unsigned short* __restrict__ wt,
    unsigned short* __restrict__ h, int n_nodes) {
    int tid = threadIdx.x;
    int wv = tid >> 6, l = tid & 63;
    int l16 = l & 15, hi = l >> 4, lk = hi * 8;
    long row0 = (long)blockIdx.x * 128 + wv * 32;

    long rmax = n_nodes - 1;
    long ra0 = row0 + l16;      if (ra0 > rmax) ra0 = rmax;
    long ra1 = row0 + 16 + l16; if (ra1 > rmax) ra1 = rmax;
    const float* xp0 = x + ra0 * IN_F + lk;
    const float* xp1 = x + ra1 * IN_F + lk;
    const unsigned short* wp = wt + l16 * IN_F + lk;   // feature l16 (+nt*16)

    f32x4 acc[2][8];
    #pragma unroll
    for (int rt = 0; rt < 2; rt++)
        #pragma unroll
        for (int nt = 0; nt < 8; nt++)
            acc[rt][nt] = (f32x4){0.f, 0.f, 0.f, 0.f};

    #pragma unroll
    for (int ks = 0; ks < 8; ks++) {
        int k0 = ks * 32;
        float4 t0 = *(const float4*)(xp0 + k0);
        float4 t1 = *(const float4*)(xp0 + k0 + 4);
        float4 t2 = *(const float4*)(xp1 + k0);
        float4 t3 = *(const float4*)(xp1 + k0 + 4);
        sh8 xb0, xb1;
        xb0[0] = (short)f2bf(t0.x); xb0[1] = (short)f2bf(t0.y);
        xb0[2] = (short)f2bf(t0.z); xb0[3] = (short)f2bf(t0.w);
        xb0[4] = (short)f2bf(t1.x); xb0[5] = (short)f2bf(t1.y);
        xb0[6] = (short)f2bf(t1.z); xb0[7] = (short)f2bf(t1.w);
        xb1[0] = (short)f2bf(t2.x); xb1[1] = (short)f2bf(t2.y);
        xb1[2] = (short)f2bf(t2.z); xb1[3] = (short)f2bf(t2.w);
        xb1[4] = (short)f2bf(t3.x); xb1[5] = (short)f2bf(t3.y);
        xb1[6] = (short)f2bf(t3.z); xb1[7] = (short)f2bf(t3.w);
        #pragma unroll
        for (int nt = 0; nt < 8; nt++) {
            sh8 aw = *(const sh8*)(wp + nt * 16 * IN_F + k0);
            acc[0][nt] = __builtin_amdgcn_mfma_f32_16x16x32_bf16(
                aw, xb0, acc[0][nt], 0, 0, 0);
            acc[1][nt] = __builtin_amdgcn_mfma_f32_16x16x32_bf16(
                aw, xb1, acc[1][nt], 0, 0, 0);
        }
    }

    #pragma unroll
    for (int rt = 0; rt < 2; rt++) {
        long row = row0 + rt * 16 + l16;
        if (row < n_nodes) {
            unsigned short* hp = h + row * OUT_F + hi * 4;
            #pragma unroll
            for (int nt = 0; nt < 8; nt++) {
                ushort4 o;
                o.x = f2bf(acc[rt][nt][0]);
                o.y = f2bf(acc[rt][nt][1]);
                o.z = f2bf(acc[rt][nt][2]);
                o.w = f2bf(acc[rt][nt][3]);
                *(ushort4*)(hp + nt * 16) = o;
            }
        }
    }
}

// ---------------- hist: T[b][k] = #edges of block b in bucket k -----------
__global__ __launch_bounds__(256) void hist_kernel(
    const int* __restrict__ erow, int* __restrict__ T,
    int n_edges, int nbuck) {
    __shared__ int lh[2048];
    int tid = threadIdx.x, b = blockIdx.x;
    for (int k = tid; k < nbuck; k += 256) lh[k] = 0;
    __syncthreads();
    int s = b * CH, e = min(s + CH, n_edges);
    for (int i = s + tid; i < e; i += 256)
        atomicAdd(&lh[erow[i] >> BSH], 1);
    __syncthreads();
    int* Tr = T + (long)b * nbuck;
    for (int k = tid; k < nbuck; k += 256) Tr[k] = lh[k];
}

// ---------------- colscan: T[b][k] -> prefix over b; colTotal[k] ----------
__global__ __launch_bounds__(256) void colscan_kernel(
    int* __restrict__ T, int* __restrict__ colTotal, int nblk, int nbuck) {
    int k = blockIdx.x * 4 + (threadIdx.x >> 6);
    int lane = threadIdx.x & 63;
    if (k >= nbuck) return;
    int carry = 0;
    for (int c = 0; c < nblk; c += 64) {
        int b = c + lane;
        int v = (b < nblk) ? T[(long)b * nbuck + k] : 0;
        int incl = v;
        #pragma unroll
        for (int off = 1; off < 64; off <<= 1) {
            int t = __shfl_up(incl, off);
            if (lane >= off) incl += t;
        }
        if (b < nblk) T[(long)b * nbuck + k] = carry + incl - v;
        carry += __shfl(incl, 63);
    }
    if (lane == 0) colTotal[k] = carry;
}

// ---------------- basescan: bucketBase = exclusive scan(colTotal) ---------
__global__ __launch_bounds__(256) void basescan_kernel(
    const int* __restrict__ colTotal, int* __restrict__ base, int nbuck) {
    __shared__ int s[256];
    int tid = threadIdx.x;
    int loc[8];
    int sum = 0;
    #pragma unroll
    for (int j = 0; j < 8; j++) {
        int i = tid * 8 + j;
        loc[j] = (i < nbuck) ? colTotal[i] : 0;
        sum += loc[j];
    }
    s[tid] = sum;
    __syncthreads();
    for (int off = 1; off < 256; off <<= 1) {
        int t = (tid >= off) ? s[tid - off] : 0;
        __syncthreads();
        s[tid] += t;
        __syncthreads();
    }
    int pre = s[tid] - sum;
    #pragma unroll
    for (int j = 0; j < 8; j++) {
        int i = tid * 8 + j;
        if (i < nbuck) base[i] = pre;
        pre += loc[j];
    }
    if (tid == 255) base[nbuck] = pre;    // == n_edges
}

// ---------------- scatter: exact positions via LDS atomics ----------------
__global__ __launch_bounds__(256) void scatter_kernel(
    const int* __restrict__ erow, const int* __restrict__ ecol,
    const float* __restrict__ eval, const int* __restrict__ T,
    const int* __restrict__ base, unsigned long long* __restrict__ epack,
    int n_edges, int nbuck) {
    __shared__ int lpos[2048];
    int tid = threadIdx.x, b = blockIdx.x;
    const int* Tr = T + (long)b * nbuck;
    for (int k = tid; k < nbuck; k += 256) lpos[k] = base[k] + Tr[k];
    __syncthreads();
    int s = b * CH, e = min(s + CH, n_edges);
    for (int i = s + tid; i < e; i += 256) {
        int r = erow[i];
        int c = ecol[i];
        float v = eval[i];
        int p = atomicAdd(&lpos[r >> BSH], 1);
        epack[p] = ((unsigned long long)__float_as_uint(v) << 32)
                 | ((unsigned)(r & 63) << 17) | (unsigned)c;
    }
}

// ---------------- bucket_rowsum: block/bucket, LDS sort, gather x8 --------
__global__ __launch_bounds__(256) void bucket_rowsum_kernel(
    const unsigned short* __restrict__ h, const int* __restrict__ base,
    const unsigned long long* __restrict__ epack,
    float* __restrict__ out, int n_nodes, int nbuck) {
    __shared__ unsigned long long sorted[CAP];
    __shared__ int lh[64], lo[64], lc[64];
    int tid = threadIdx.x, k = blockIdx.x;
    int s = base[k], e = base[k + 1];
    int size = e - s;
    int wv = tid >> 6, lane = tid & 63;

    if (tid < 64) { lh[tid] = 0; lc[tid] = 0; }
    __syncthreads();
    for (int i = tid; i < size; i += 256) {
        unsigned lo32 = (unsigned)(epack[s + i] & 0xffffffffu);
        atomicAdd(&lh[(lo32 >> 17) & 63], 1);
    }
    __syncthreads();
    if (tid < 64) {
        int v = lh[tid];
        int incl = v;
        #pragma unroll
        for (int off = 1; off < 64; off <<= 1) {
            int t = __shfl_up(incl, off);
            if (lane >= off) incl += t;
        }
        lo[tid] = incl - v;
    }
    __syncthreads();
    bool fits = (size <= CAP);
    if (fits) {
        for (int i = tid; i < size; i += 256) {
            unsigned long long ed = epack[s + i];
            int r = (int)((ed >> 17) & 63);
            int p = atomicAdd(&lc[r], 1) + lo[r];
            sorted[p] = ed;
        }
    }
    __syncthreads();

#define GSTEP(EV)                                                            \
    {                                                                        \
        unsigned hv = *((const unsigned*)(h + (long)((EV) & 0x1ffffu) * OUT_F) + lane); \
        float vv = __uint_as_float((unsigned)((EV) >> 32));                  \
        a0 += vv * bf2f((unsigned short)(hv & 0xffff));                      \
        a1 += vv * bf2f((unsigned short)(hv >> 16));                         \
    }

    for (int rr = 0; rr < 16; rr++) {
        int r = wv * 16 + rr;
        long row = (long)k * 64 + r;
        if (row >= n_nodes) break;
        int rs = lo[r], cnt = lh[r];
        float a0 = 0.f, a1 = 0.f;
        if (fits) {
            int j = 0;
            for (; j + 8 <= cnt; j += 8) {
                unsigned long long e0 = sorted[rs + j];
                unsigned long long e1 = sorted[rs + j + 1];
                unsigned long long e2 = sorted[rs + j + 2];
                unsigned long long e3 = sorted[rs + j + 3];
                unsigned long long e4 = sorted[rs + j + 4];
                unsigned long long e5 = sorted[rs + j + 5];
                unsigned long long e6 = sorted[rs + j + 6];
                unsigned long long e7 = sorted[rs + j + 7];
                GSTEP(e0) GSTEP(e1) GSTEP(e2) GSTEP(e3)
                GSTEP(e4) GSTEP(e5) GSTEP(e6) GSTEP(e7)
            }
            for (; j + 4 <= cnt; j += 4) {
                unsigned long long e0 = sorted[rs + j];
                unsigned long long e1 = sorted[rs + j + 1];
                unsigned long long e2 = sorted[rs + j + 2];
                unsigned long long e3 = sorted[rs + j + 3];
                GSTEP(e0) GSTEP(e1) GSTEP(e2) GSTEP(e3)
            }
            for (; j < cnt; j++) {
                unsigned long long e0 = sorted[rs + j];
                GSTEP(e0)
            }
        } else {
            for (int i = 0; i < size; i++) {
                unsigned long long ed = epack[s + i];
                if ((int)((ed >> 17) & 63) == r) GSTEP(ed)
            }
        }
        float2 o; o.x = a0; o.y = a1;
        *(float2*)(out + row * OUT_F + lane * 2) = o;
    }
#undef GSTEP
}

extern "C" void kernel_launch(void* const* d_in, const int* in_sizes, int n_in,
                              void* d_out, int out_size, void* d_ws, size_t ws_size,
                              hipStream_t stream) {
    const float* x    = (const float*)d_in[0];
    const float* w    = (const float*)d_in[1];
    const int*   erow = (const int*)d_in[2];
    const int*   ecol = (const int*)d_in[3];
    const float* eval = (const float*)d_in[4];
    float* out = (float*)d_out;

    int n_nodes = in_sizes[0] / IN_F;
    int n_edges = in_sizes[2];
    int nbuck = (n_nodes + 63) >> BSH;            // 1563
    int nblk  = (n_edges + CH - 1) / CH;          // 391

    // workspace layout (256B aligned)
    char* p = (char*)d_ws;
    auto alloc = [&](size_t bytes) {
        char* q = p;
        p += (bytes + 255) & ~(size_t)255;
        return q;
    };
    unsigned short* h  = (unsigned short*)alloc((size_t)n_nodes * OUT_F * 2);
    int* T        = (int*)alloc((size_t)nblk * nbuck * 4);
    int* colTotal = (int*)alloc((size_t)nbuck * 4);
    int* base     = (int*)alloc((size_t)(nbuck + 1) * 4);
    unsigned long long* epack = (unsigned long long*)alloc((size_t)n_edges * 8);
    unsigned short* wt = (unsigned short*)alloc((size_t)IN_F * OUT_F * 2);

    wt_prep_kernel<<<dim3((IN_F * OUT_F) / 256), 256, 0, stream>>>(w, wt);
    gemm_mfma_kernel<<<dim3((n_nodes + 127) / 128), 256, 0, stream>>>(
        x, wt, h, n_nodes);

    hist_kernel<<<dim3(nblk), 256, 0, stream>>>(erow, T, n_edges, nbuck);
    colscan_kernel<<<dim3((nbuck + 3) / 4), 256, 0, stream>>>(
        T, colTotal, nblk, nbuck);
    basescan_kernel<<<dim3(1), 256, 0, stream>>>(colTotal, base, nbuck);
    scatter_kernel<<<dim3(nblk), 256, 0, stream>>>(
        erow, ecol, eval, T, base, epack, n_edges, nbuck);

    bucket_rowsum_kernel<<<dim3(nbuck), 256, 0, stream>>>(
        h, base, epack, out, n_nodes, nbuck);
}

// Round 19
// 164.716 us; speedup vs baseline: 1.0691x; 1.0189x over previous
//
#include <hip/hip_runtime.h>
#include <hip/hip_bf16.h>

// GCNConv: out = segment_sum(edge_vals * (x@W)[edge_col], edge_row)
// Phase 1: Wt = bf16(W^T); FUSED {h = x@W bf16 MFMA col-split} || {hist}
//          (hist is LDS-atomic-only -> overlaps cleanly; 1:5 interleave).
// Phase 2: colscan -> basescan -> scatter (LDS atomics only) ->
//          bucket_rowsum (LDS sort + gather x8). All proven at 165us; this
//          round only removes the serial hist dispatch.

#define IN_F  256
#define OUT_F 128
#define BSH   6        // 64 rows per bucket
#define CH    4096     // edges per chunk block
#define CAP   1536     // LDS sorted-bucket capacity (avg 1024, +16 sigma)

typedef __attribute__((ext_vector_type(8))) short sh8;
typedef __attribute__((ext_vector_type(4))) float f32x4;

__device__ __forceinline__ unsigned short f2bf(float f) {
    unsigned u = __float_as_uint(f);
    unsigned r = u + 0x7fff + ((u >> 16) & 1);   // round-to-nearest-even
    return (unsigned short)(r >> 16);
}
__device__ __forceinline__ float bf2f(unsigned short s) {
    return __uint_as_float(((unsigned)s) << 16);
}

// ---------------- Wt[n][k] = bf16(W[k][n]) ----------------
__global__ __launch_bounds__(256) void wt_prep_kernel(
    const float* __restrict__ w, unsigned short* __restrict__ wt) {
    int i = blockIdx.x * 256 + threadIdx.x;     // 32768 elements
    int k = i >> 7, n = i & 127;
    wt[n * IN_F + k] = f2bf(w[i]);
}

// -------- FUSED: hist (every R-th block) || gemm col-split (rest) ---------
// gemm: blockIdx -> (row_tile, ch); 128 rows x 64 cols; R12-proven body.
// hist: chunk c; LDS histogram over nbuck buckets -> T[c][*]. No global atomics.
__global__ __launch_bounds__(256) void fused_gemm_hist_kernel(
    const float* __restrict__ x, const unsigned short* __restrict__ wt,
    unsigned short* __restrict__ h, int n_nodes,
    const int* __restrict__ erow, int* __restrict__ T,
    int n_edges, int nbuck, int nblk, int nrow_tiles, int R) {
    __shared__ int lh[2048];
    int g = blockIdx.x, tid = threadIdx.x;
    int hq = g / R;
    bool is_hist = ((g % R) == 0) && (hq < nblk);

    if (is_hist) {
        // ---------------- hist ----------------
        int b = hq;
        for (int k = tid; k < nbuck; k += 256) lh[k] = 0;
        __syncthreads();
        int s = b * CH, e = min(s + CH, n_edges);
        for (int i = s + tid; i < e; i += 256)
            atomicAdd(&lh[erow[i] >> BSH], 1);
        __syncthreads();
        int* Tr = T + (long)b * nbuck;
        for (int k = tid; k < nbuck; k += 256) Tr[k] = lh[k];
        return;
    }

    // ---------------- gemm (R12 body) ----------------
    int nhist_before = min(hq + ((g % R) ? 1 : 0), nblk);
    int gemm_idx = g - nhist_before;
    int rt_idx = gemm_idx % nrow_tiles;
    int ch = gemm_idx / nrow_tiles;              // 0 or 1
    if (ch > 1) return;

    int wv = tid >> 6, l = tid & 63;
    int l16 = l & 15, lk = (l >> 4) * 8;
    long row0 = (long)rt_idx * 128 + wv * 32;

    long rmax = n_nodes - 1;
    long ra0 = row0 + l16;      if (ra0 > rmax) ra0 = rmax;
    long ra1 = row0 + 16 + l16; if (ra1 > rmax) ra1 = rmax;
    const float* xp0 = x + ra0 * IN_F + lk;
    const float* xp1 = x + ra1 * IN_F + lk;
    const unsigned short* wp = wt + (ch * 64 + l16) * IN_F + lk;

    f32x4 acc[2][4];
    #pragma unroll
    for (int rt = 0; rt < 2; rt++)
        #pragma unroll
        for (int nt = 0; nt < 4; nt++)
            acc[rt][nt] = (f32x4){0.f, 0.f, 0.f, 0.f};

    #pragma unroll
    for (int ks = 0; ks < 8; ks++) {
        int k0 = ks * 32;
        float4 t0 = *(const float4*)(xp0 + k0);
        float4 t1 = *(const float4*)(xp0 + k0 + 4);
        float4 t2 = *(const float4*)(xp1 + k0);
        float4 t3 = *(const float4*)(xp1 + k0 + 4);
        sh8 a0, a1;
        a0[0] = (short)f2bf(t0.x); a0[1] = (short)f2bf(t0.y);
        a0[2] = (short)f2bf(t0.z); a0[3] = (short)f2bf(t0.w);
        a0[4] = (short)f2bf(t1.x); a0[5] = (short)f2bf(t1.y);
        a0[6] = (short)f2bf(t1.z); a0[7] = (short)f2bf(t1.w);
        a1[0] = (short)f2bf(t2.x); a1[1] = (short)f2bf(t2.y);
        a1[2] = (short)f2bf(t2.z); a1[3] = (short)f2bf(t2.w);
        a1[4] = (short)f2bf(t3.x); a1[5] = (short)f2bf(t3.y);
        a1[6] = (short)f2bf(t3.z); a1[7] = (short)f2bf(t3.w);
        #pragma unroll
        for (int nt = 0; nt < 4; nt++) {
            sh8 b = *(const sh8*)(wp + nt * 16 * IN_F + k0);
            acc[0][nt] = __builtin_amdgcn_mfma_f32_16x16x32_bf16(
                a0, b, acc[0][nt], 0, 0, 0);
            acc[1][nt] = __builtin_amdgcn_mfma_f32_16x16x32_bf16(
                a1, b, acc[1][nt], 0, 0, 0);
        }
    }

    int rbase = (l >> 4) * 4;
    #pragma unroll
    for (int rt = 0; rt < 2; rt++) {
        #pragma unroll
        for (int j = 0; j < 4; j++) {
            long r = row0 + rt * 16 + rbase + j;
            if (r < n_nodes) {
                unsigned short* hp = h + r * OUT_F + ch * 64 + l16;
                #pragma unroll
                for (int nt = 0; nt < 4; nt++)
                    hp[nt * 16] = f2bf(acc[rt][nt][j]);
            }
        }
    }
}

// ---------------- colscan: T[b][k] -> prefix over b; colTotal[k] ----------
__global__ __launch_bounds__(256) void colscan_kernel(
    int* __restrict__ T, int* __restrict__ colTotal, int nblk, int nbuck) {
    int k = blockIdx.x * 4 + (threadIdx.x >> 6);
    int lane = threadIdx.x & 63;
    if (k >= nbuck) return;
    int carry = 0;
    for (int c = 0; c < nblk; c += 64) {
        int b = c + lane;
        int v = (b < nblk) ? T[(long)b * nbuck + k] : 0;
        int incl = v;
        #pragma unroll
        for (int off = 1; off < 64; off <<= 1) {
            int t = __shfl_up(incl, off);
            if (lane >= off) incl += t;
        }
        if (b < nblk) T[(long)b * nbuck + k] = carry + incl - v;
        carry += __shfl(incl, 63);
    }
    if (lane == 0) colTotal[k] = carry;
}

// ---------------- basescan: bucketBase = exclusive scan(colTotal) ---------
__global__ __launch_bounds__(256) void basescan_kernel(
    const int* __restrict__ colTotal, int* __restrict__ base, int nbuck) {
    __shared__ int s[256];
    int tid = threadIdx.x;
    int loc[8];
    int sum = 0;
    #pragma unroll
    for (int j = 0; j < 8; j++) {
        int i = tid * 8 + j;
        loc[j] = (i < nbuck) ? colTotal[i] : 0;
        sum += loc[j];
    }
    s[tid] = sum;
    __syncthreads();
    for (int off = 1; off < 256; off <<= 1) {
        int t = (tid >= off) ? s[tid - off] : 0;
        __syncthreads();
        s[tid] += t;
        __syncthreads();
    }
    int pre = s[tid] - sum;
    #pragma unroll
    for (int j = 0; j < 8; j++) {
        int i = tid * 8 + j;
        if (i < nbuck) base[i] = pre;
        pre += loc[j];
    }
    if (tid == 255) base[nbuck] = pre;    // == n_edges
}

// ---------------- scatter: exact positions via LDS atomics ----------------
__global__ __launch_bounds__(256) void scatter_kernel(
    const int* __restrict__ erow, const int* __restrict__ ecol,
    const float* __restrict__ eval, const int* __restrict__ T,
    const int* __restrict__ base, unsigned long long* __restrict__ epack,
    int n_edges, int nbuck) {
    __shared__ int lpos[2048];
    int tid = threadIdx.x, b = blockIdx.x;
    const int* Tr = T + (long)b * nbuck;
    for (int k = tid; k < nbuck; k += 256) lpos[k] = base[k] + Tr[k];
    __syncthreads();
    int s = b * CH, e = min(s + CH, n_edges);
    for (int i = s + tid; i < e; i += 256) {
        int r = erow[i];
        int c = ecol[i];
        float v = eval[i];
        int p = atomicAdd(&lpos[r >> BSH], 1);
        epack[p] = ((unsigned long long)__float_as_uint(v) << 32)
                 | ((unsigned)(r & 63) << 17) | (unsigned)c;
    }
}

// ---------------- bucket_rowsum: block/bucket, LDS sort, gather x8 --------
__global__ __launch_bounds__(256) void bucket_rowsum_kernel(
    const unsigned short* __restrict__ h, const int* __restrict__ base,
    const unsigned long long* __restrict__ epack,
    float* __restrict__ out, int n_nodes, int nbuck) {
    __shared__ unsigned long long sorted[CAP];
    __shared__ int lh[64], lo[64], lc[64];
    int tid = threadIdx.x, k = blockIdx.x;
    int s = base[k], e = base[k + 1];
    int size = e - s;
    int wv = tid >> 6, lane = tid & 63;

    if (tid < 64) { lh[tid] = 0; lc[tid] = 0; }
    __syncthreads();
    for (int i = tid; i < size; i += 256) {
        unsigned lo32 = (unsigned)(epack[s + i] & 0xffffffffu);
        atomicAdd(&lh[(lo32 >> 17) & 63], 1);
    }
    __syncthreads();
    if (tid < 64) {
        int v = lh[tid];
        int incl = v;
        #pragma unroll
        for (int off = 1; off < 64; off <<= 1) {
            int t = __shfl_up(incl, off);
            if (lane >= off) incl += t;
        }
        lo[tid] = incl - v;
    }
    __syncthreads();
    bool fits = (size <= CAP);
    if (fits) {
        for (int i = tid; i < size; i += 256) {
            unsigned long long ed = epack[s + i];
            int r = (int)((ed >> 17) & 63);
            int p = atomicAdd(&lc[r], 1) + lo[r];
            sorted[p] = ed;
        }
    }
    __syncthreads();

#define GSTEP(EV)                                                            \
    {                                                                        \
        unsigned hv = *((const unsigned*)(h + (long)((EV) & 0x1ffffu) * OUT_F) + lane); \
        float vv = __uint_as_float((unsigned)((EV) >> 32));                  \
        a0 += vv * bf2f((unsigned short)(hv & 0xffff));                      \
        a1 += vv * bf2f((unsigned short)(hv >> 16));                         \
    }

    for (int rr = 0; rr < 16; rr++) {
        int r = wv * 16 + rr;
        long row = (long)k * 64 + r;
        if (row >= n_nodes) break;
        int rs = lo[r], cnt = lh[r];
        float a0 = 0.f, a1 = 0.f;
        if (fits) {
            int j = 0;
            for (; j + 8 <= cnt; j += 8) {
                unsigned long long e0 = sorted[rs + j];
                unsigned long long e1 = sorted[rs + j + 1];
                unsigned long long e2 = sorted[rs + j + 2];
                unsigned long long e3 = sorted[rs + j + 3];
                unsigned long long e4 = sorted[rs + j + 4];
                unsigned long long e5 = sorted[rs + j + 5];
                unsigned long long e6 = sorted[rs + j + 6];
                unsigned long long e7 = sorted[rs + j + 7];
                GSTEP(e0) GSTEP(e1) GSTEP(e2) GSTEP(e3)
                GSTEP(e4) GSTEP(e5) GSTEP(e6) GSTEP(e7)
            }
            for (; j + 4 <= cnt; j += 4) {
                unsigned long long e0 = sorted[rs + j];
                unsigned long long e1 = sorted[rs + j + 1];
                unsigned long long e2 = sorted[rs + j + 2];
                unsigned long long e3 = sorted[rs + j + 3];
                GSTEP(e0) GSTEP(e1) GSTEP(e2) GSTEP(e3)
            }
            for (; j < cnt; j++) {
                unsigned long long e0 = sorted[rs + j];
                GSTEP(e0)
            }
        } else {
            for (int i = 0; i < size; i++) {
                unsigned long long ed = epack[s + i];
                if ((int)((ed >> 17) & 63) == r) GSTEP(ed)
            }
        }
        float2 o; o.x = a0; o.y = a1;
        *(float2*)(out + row * OUT_F + lane * 2) = o;
    }
#undef GSTEP
}

extern "C" void kernel_launch(void* const* d_in, const int* in_sizes, int n_in,
                              void* d_out, int out_size, void* d_ws, size_t ws_size,
                              hipStream_t stream) {
    const float* x    = (const float*)d_in[0];
    const float* w    = (const float*)d_in[1];
    const int*   erow = (const int*)d_in[2];
    const int*   ecol = (const int*)d_in[3];
    const float* eval = (const float*)d_in[4];
    float* out = (float*)d_out;

    int n_nodes = in_sizes[0] / IN_F;
    int n_edges = in_sizes[2];
    int nbuck = (n_nodes + 63) >> BSH;            // 1563
    int nblk  = (n_edges + CH - 1) / CH;          // 391

    // workspace layout (256B aligned)
    char* p = (char*)d_ws;
    auto alloc = [&](size_t bytes) {
        char* q = p;
        p += (bytes + 255) & ~(size_t)255;
        return q;
    };
    unsigned short* h  = (unsigned short*)alloc((size_t)n_nodes * OUT_F * 2);
    int* T        = (int*)alloc((size_t)nblk * nbuck * 4);
    int* colTotal = (int*)alloc((size_t)nbuck * 4);
    int* base     = (int*)alloc((size_t)(nbuck + 1) * 4);
    unsigned long long* epack = (unsigned long long*)alloc((size_t)n_edges * 8);
    unsigned short* wt = (unsigned short*)alloc((size_t)IN_F * OUT_F * 2);

    wt_prep_kernel<<<dim3((IN_F * OUT_F) / 256), 256, 0, stream>>>(w, wt);

    int nrow_tiles = (n_nodes + 127) / 128;       // 782
    int ngemm = nrow_tiles * 2;                   // 1564
    int total = ngemm + nblk;                     // 1955
    int R = (total + nblk - 1) / nblk;            // 5
    fused_gemm_hist_kernel<<<dim3(total), 256, 0, stream>>>(
        x, wt, h, n_nodes, erow, T, n_edges, nbuck, nblk, nrow_tiles, R);

    colscan_kernel<<<dim3((nbuck + 3) / 4), 256, 0, stream>>>(
        T, colTotal, nblk, nbuck);
    basescan_kernel<<<dim3(1), 256, 0, stream>>>(colTotal, base, nbuck);
    scatter_kernel<<<dim3(nblk), 256, 0, stream>>>(
        erow, ecol, eval, T, base, epack, n_edges, nbuck);

    bucket_rowsum_kernel<<<dim3(nbuck), 256, 0, stream>>>(
        h, base, epack, out, n_nodes, nbuck);
}